// Round 7
// baseline (286.902 us; speedup 1.0000x reference)
//
#include <hip/hip_runtime.h>
#include <stdint.h>

typedef uint16_t u16;
typedef _Float16 f16;
typedef __attribute__((ext_vector_type(8)))  f16      f16x8;
typedef __attribute__((ext_vector_type(2)))  __fp16   h16x2;   // native type of cvt_pkrtz
typedef __attribute__((ext_vector_type(8)))  uint16_t u16x8;
typedef __attribute__((ext_vector_type(4)))  uint16_t u16x4;
typedef __attribute__((ext_vector_type(2)))  uint32_t u32x2;
typedef __attribute__((ext_vector_type(4)))  uint32_t u32x4;
typedef __attribute__((ext_vector_type(4)))  float    f32x4;

#define LOG2E 1.44269504088896340736f
#define MFMA16F(a, b, c) __builtin_amdgcn_mfma_f32_16x16x32_f16((a), (b), (c), 0, 0, 0)

__device__ __forceinline__ u16 f2h(float f) {
  f16 h = (f16)f;
  return __builtin_bit_cast(u16, h);
}
__device__ __forceinline__ uint32_t pk2(float a, float b) {  // packed f32->f16 RTZ
  h16x2 h = __builtin_amdgcn_cvt_pkrtz(a, b);
  return __builtin_bit_cast(uint32_t, h);
}

// LDS tiles: [rows][64 f16] = 8 chunks of 16B per row, chunk XOR-swizzled by row&7.
__device__ __forceinline__ f16x8 ldsFrag(const u16* base, int row, int chunk) {
  const u16* p = base + row * 64 + ((chunk ^ (row & 7)) << 3);
  u16x8 raw = *(const u16x8*)p;
  return __builtin_bit_cast(f16x8, raw);
}

// async global->LDS DMA, 16B/lane; LDS dest = wave-uniform base + lane*16.
__device__ __forceinline__ void dma16(const u16* g, u16* l) {
  __builtin_amdgcn_global_load_lds(
      (const __attribute__((address_space(1))) uint32_t*)g,
      (__attribute__((address_space(3))) uint32_t*)l, 16, 0, 0);
}

// ---------------- kernel 0: pack weights ----------------
// Wt[n][k] f16 (n<64: Wf*log2e, n<128: Wg, else Wh), biasc[n] fp32 (bf*log2e).
__global__ __launch_bounds__(256) void pack_weights2(
    const float* __restrict__ Wf, const float* __restrict__ Wg,
    const float* __restrict__ Wh, const float* __restrict__ bfv,
    const float* __restrict__ bgv, const float* __restrict__ bhv,
    u16* __restrict__ Wt, float* __restrict__ biasc) {
  __shared__ u16 T[64 * 64];       // [k][n]
  const int nt = blockIdx.x >> 3;  // 0..9
  const int kt = blockIdx.x & 7;   // 0..7
  const int n0 = nt * 64, k0 = kt * 64;
  const float* src; int stride, cbase; float scale = 1.0f;
  if (nt == 0)      { src = Wf; stride = 64;  cbase = 0;        scale = LOG2E; }
  else if (nt == 1) { src = Wg; stride = 64;  cbase = 0; }
  else              { src = Wh; stride = 512; cbase = n0 - 128; }
  const int t = threadIdx.x;
  const int cl = (t & 15) * 4, r0 = t >> 4;
#pragma unroll
  for (int j = 0; j < 4; ++j) {
    int r = r0 + j * 16;
    f32x4 v = *(const f32x4*)(src + (size_t)(k0 + r) * stride + cbase + cl);
    u16x4 o;
#pragma unroll
    for (int i = 0; i < 4; ++i) o[i] = f2h(v[i] * scale);
    *(u16x4*)(T + r * 64 + cl) = o;
  }
  __syncthreads();
  const int n = t >> 2, kq = (t & 3) * 16;
  u16x8 a, b2;
#pragma unroll
  for (int i = 0; i < 8; ++i) { a[i] = T[(kq + i) * 64 + n]; b2[i] = T[(kq + 8 + i) * 64 + n]; }
  *(u16x8*)(Wt + (size_t)(n0 + n) * 512 + k0 + kq) = a;
  *(u16x8*)(Wt + (size_t)(n0 + n) * 512 + k0 + kq + 8) = b2;
  if (kt == 0 && t < 64) {
    float bv = (nt == 0) ? bfv[t] * LOG2E : (nt == 1) ? bgv[t] : bhv[cbase + t];
    biasc[n0 + t] = bv;
  }
}

// ---------------- kernel 1: projection GEMM v3 ----------------
// M=128 x N=128 tiles (640 blocks). A-frags DIRECT from global x (no A-LDS
// stage; packed cvt_pkrtz f32->f16). B (Wt) via DMA double-buffer -> ONE
// barrier per K-step. h epilogue: LDS-bounce transpose, coalesced ht stores.
__global__ __launch_bounds__(256, 2) void proj_gemm3(
    const float* __restrict__ x, const u16* __restrict__ Wt,
    const float* __restrict__ biasc,
    u16* __restrict__ fo, u16* __restrict__ go, u16* __restrict__ ht) {
  __shared__ u16 smem[2 * 128 * 64];   // 32 KB: B dbuf; reused as T after loop
  const int t = threadIdx.x, lane = t & 63, w = t >> 6;
  const int m0 = blockIdx.x * 128, n0 = blockIdx.y * 128;
  const int wr = w >> 1, wc = w & 1;
  const int l15 = lane & 15, l4 = lane >> 4;
  const int dmarow = lane >> 3, dmachunk = (lane & 7) ^ (lane >> 3);

  f32x4 acc[4][4];
#pragma unroll
  for (int i = 0; i < 4; ++i)
#pragma unroll
    for (int j = 0; j < 4; ++j) acc[i][j] = (f32x4)(0.f);

  auto stage_b = [&](int kb) {       // B tile [128 n][64 k] -> buf[kb&1]
    u16* dst = smem + (kb & 1) * 128 * 64;
#pragma unroll
    for (int ii = 0; ii < 4; ++ii) {
      int rw = w * 32 + ii * 8;
      const u16* src = Wt + (size_t)(n0 + rw + dmarow) * 512 + kb * 64 + dmachunk * 8;
      dma16(src, dst + rw * 64);
    }
  };

  stage_b(0);
  __syncthreads();

  for (int kb = 0; kb < 8; ++kb) {
    if (kb < 7) stage_b(kb + 1);
    const int k0 = kb * 64;
    const u16* bbuf = smem + (kb & 1) * 128 * 64;
    // A-frags direct from x (row reuse across 4 nt)
    f16x8 af[4][2];
#pragma unroll
    for (int mt = 0; mt < 4; ++mt)
#pragma unroll
      for (int ks = 0; ks < 2; ++ks) {
        const float* s = x + (size_t)(m0 + wr * 64 + mt * 16 + l15) * 512 + k0 + ks * 32 + l4 * 8;
        f32x4 a0 = *(const f32x4*)s;
        f32x4 a1 = *(const f32x4*)(s + 4);
        u32x4 pkd;
        pkd[0] = pk2(a0[0], a0[1]); pkd[1] = pk2(a0[2], a0[3]);
        pkd[2] = pk2(a1[0], a1[1]); pkd[3] = pk2(a1[2], a1[3]);
        af[mt][ks] = __builtin_bit_cast(f16x8, pkd);
      }
#pragma unroll
    for (int ks = 0; ks < 2; ++ks) {
      f16x8 bq[4];
#pragma unroll
      for (int nt = 0; nt < 4; ++nt) bq[nt] = ldsFrag(bbuf, wc * 64 + nt * 16 + l15, ks * 4 + l4);
#pragma unroll
      for (int mt = 0; mt < 4; ++mt)
#pragma unroll
        for (int nt = 0; nt < 4; ++nt) acc[mt][nt] = MFMA16F(af[mt][ks], bq[nt], acc[mt][nt]);
    }
    __syncthreads();   // waves done reading buf[kb&1]; stage(kb+1) DMA drained
  }

  if (n0 >= 128) {
    // ---- h path: LDS-bounce transpose -> coalesced ht stores ----
#pragma unroll
    for (int nt = 0; nt < 4; ++nt) {
      int nl = wc * 64 + nt * 16 + l15;      // n within block (0..127)
      float bv = biasc[n0 + nl];
#pragma unroll
      for (int mt = 0; mt < 4; ++mt) {
        int mb = wr * 64 + mt * 16 + (l4 << 2);
        f32x4 a = acc[mt][nt];
        u16x4 v;
#pragma unroll
        for (int r = 0; r < 4; ++r) v[r] = f2h(a[r] + bv);
        u16* dst = smem + nl * 128 + (((mb >> 3) ^ (nl & 7)) << 3) + (mb & 7);
        *(u16x4*)dst = v;
      }
    }
    __syncthreads();
    const int bb = m0 >> 12, posb = m0 & 4095;
    const int row0 = t >> 4, c16 = t & 15;
#pragma unroll
    for (int j = 0; j < 8; ++j) {
      int rr = row0 + j * 16;
      u16x8 v = *(const u16x8*)(smem + rr * 128 + ((c16 ^ (rr & 7)) << 3));
      int vcol = n0 - 128 + rr;
      *(u16x8*)(ht + ((size_t)(bb * 512 + vcol) << 12) + posb + c16 * 8) = v;
    }
  } else {
    // ---- f/g path ----
#pragma unroll
    for (int nt = 0; nt < 4; ++nt) {
      int n = wc * 64 + nt * 16 + l15;
      float bv = biasc[n];
#pragma unroll
      for (int mt = 0; mt < 4; ++mt) {
        int mrow = m0 + wr * 64 + mt * 16 + (l4 << 2);
        f32x4 a = acc[mt][nt];
        if (n < 64) {
#pragma unroll
          for (int r = 0; r < 4; ++r) fo[(size_t)(mrow + r) * 64 + n] = f2h(a[r] + bv);
        } else {
#pragma unroll
          for (int r = 0; r < 4; ++r) go[(size_t)(mrow + r) * 64 + (n - 64)] = f2h(a[r] + bv);
        }
      }
    }
  }
}

// ---------------- kernel 2: attention v6 — intra-wave pipelined ----------
// 512 blocks x 4 waves (2/CU). Q=64 x VC=256, Kt=64 keys/iter, slice i&7->XCD.
// Per-iter program order: S-MFMA(k+1) -> PV-MFMA(k) [one ~40-MFMA burst/wave]
// -> issue hb(k+1)+g(k+2) -> exp(k+1)+P-write(k+1) [VALU in MFMA shadow]
// -> barrier. hb consumed from regs loaded a FULL iter earlier (no post-
// barrier vmem wait); prefetches merely complete at the barrier drain.
__global__ __launch_bounds__(256, 2) void attn6(
    const f16* __restrict__ fq, const f16* __restrict__ gk,
    const f16* __restrict__ ht, const float* __restrict__ x,
    const float* __restrict__ gamma_p, float* __restrict__ out) {
  __shared__ u16 lds_p[2][64 * 64];    // P dbuf, swizzled [q][key]
  __shared__ float lds_red[4 * 64];
  __shared__ float lds_linv[64];

  const int i = blockIdx.x;            // 512 blocks
  const int slice = i & 7;             // XCD-aligned: 2MB ht slice per XCD
  const int b = slice >> 1, vq = slice & 1;
  const int qb = i >> 3;               // 0..63
  const int q0 = qb * 64, vc0 = vq * 256;

  const int t = threadIdx.x, lane = t & 63, w = t >> 6;
  const int l15 = lane & 15, l4 = lane >> 4;
  const float gamma = gamma_p[0];

  const f16* gkb = gk + ((size_t)(b * 4096) + w * 16 + l15) * 64 + l4 * 8;
  const f16* htw = ht + ((size_t)(b * 512 + vc0 + w * 64 + l15)) * 4096 + l4 * 8;

  // f B-frags (S^T): all 64 q of this block, pinned
  f16x8 fB[4][2];
#pragma unroll
  for (int qt = 0; qt < 4; ++qt)
#pragma unroll
    for (int ks = 0; ks < 2; ++ks)
      fB[qt][ks] = *(const f16x8*)(fq + (size_t)(b * 4096 + q0 + qt * 16 + l15) * 64 + ks * 32 + l4 * 8);

  f32x4 oacc[4][4];
#pragma unroll
  for (int qt = 0; qt < 4; ++qt)
#pragma unroll
    for (int ct = 0; ct < 4; ++ct) oacc[qt][ct] = (f32x4)(0.f);
  float lrun[4] = {0.f, 0.f, 0.f, 0.f};

  // ---- prologue: S(0), prefetch gA(1), hb(0), write P(0) ----
  f16x8 gAn[2];
  gAn[0] = *(const f16x8*)(gkb);
  gAn[1] = *(const f16x8*)(gkb + 32);
  f32x4 sacc[4];
#pragma unroll
  for (int qt = 0; qt < 4; ++qt) sacc[qt] = (f32x4)(0.f);
#pragma unroll
  for (int ks = 0; ks < 2; ++ks)
#pragma unroll
    for (int qt = 0; qt < 4; ++qt) sacc[qt] = MFMA16F(gAn[ks], fB[qt][ks], sacc[qt]);
  gAn[0] = *(const f16x8*)(gkb + (size_t)64 * 64);
  gAn[1] = *(const f16x8*)(gkb + (size_t)64 * 64 + 32);
  f16x8 hbv[2][4];
#pragma unroll
  for (int ks = 0; ks < 2; ++ks)
#pragma unroll
    for (int ct = 0; ct < 4; ++ct)
      hbv[ks][ct] = *(const f16x8*)(htw + (size_t)(ct * 16) * 4096 + ks * 32);
  {
    u16* pbuf = lds_p[0];
#pragma unroll
    for (int qt = 0; qt < 4; ++qt) {
      f32x4 p;
#pragma unroll
      for (int r = 0; r < 4; ++r) p[r] = __builtin_amdgcn_exp2f(sacc[qt][r] - 12.0f);
      lrun[qt] += (p[0] + p[1]) + (p[2] + p[3]);
      u32x2 pkd; pkd[0] = pk2(p[0], p[1]); pkd[1] = pk2(p[2], p[3]);
      int row = qt * 16 + l15, keyb = w * 16 + (l4 << 2);
      *(u32x2*)(pbuf + row * 64 + (((keyb >> 3) ^ (row & 7)) << 3) + (keyb & 7)) =
          pkd;
    }
  }
  __syncthreads();

  // ---- main loop: iters 0..62 (PV(63) peeled) ----
  for (int kt = 0; kt < 63; ++kt) {
    // S(kt+1): one MFMA burst, gAn loaded an iter ago
    f32x4 sn[4];
#pragma unroll
    for (int qt = 0; qt < 4; ++qt) sn[qt] = (f32x4)(0.f);
#pragma unroll
    for (int ks = 0; ks < 2; ++ks)
#pragma unroll
      for (int qt = 0; qt < 4; ++qt) sn[qt] = MFMA16F(gAn[ks], fB[qt][ks], sn[qt]);
    // PV(kt): P from LDS buf[kt&1], hb from regs (loaded last iter)
    const u16* pbuf = lds_p[kt & 1];
#pragma unroll
    for (int ks = 0; ks < 2; ++ks) {
      f16x8 pf[4];
#pragma unroll
      for (int qt = 0; qt < 4; ++qt) pf[qt] = ldsFrag(pbuf, qt * 16 + l15, ks * 4 + l4);
#pragma unroll
      for (int qt = 0; qt < 4; ++qt)
#pragma unroll
        for (int ct = 0; ct < 4; ++ct)
          oacc[qt][ct] = MFMA16F(pf[qt], hbv[ks][ct], oacc[qt][ct]);
    }
    // prefetch: gA(kt+2), hb(kt+1) — consumed next iter, complete at barrier
    if (kt < 62) {
      gAn[0] = *(const f16x8*)(gkb + (size_t)(kt + 2) * 64 * 64);
      gAn[1] = *(const f16x8*)(gkb + (size_t)(kt + 2) * 64 * 64 + 32);
    }
    const size_t hoff = (size_t)(kt + 1) * 64;
#pragma unroll
    for (int ks = 0; ks < 2; ++ks)
#pragma unroll
      for (int ct = 0; ct < 4; ++ct)
        hbv[ks][ct] = *(const f16x8*)(htw + (size_t)(ct * 16) * 4096 + hoff + ks * 32);
    // exp(kt+1) + P-write (VALU, issues in MFMA-backlog shadow)
    u16* wbuf = lds_p[(kt + 1) & 1];
#pragma unroll
    for (int qt = 0; qt < 4; ++qt) {
      f32x4 p;
#pragma unroll
      for (int r = 0; r < 4; ++r) p[r] = __builtin_amdgcn_exp2f(sn[qt][r] - 12.0f);
      lrun[qt] += (p[0] + p[1]) + (p[2] + p[3]);
      u32x2 pkd; pkd[0] = pk2(p[0], p[1]); pkd[1] = pk2(p[2], p[3]);
      int row = qt * 16 + l15, keyb = w * 16 + (l4 << 2);
      *(u32x2*)(wbuf + row * 64 + (((keyb >> 3) ^ (row & 7)) << 3) + (keyb & 7)) =
          pkd;
    }
    __syncthreads();
  }
  // ---- tail: PV(63) ----
  {
    const u16* pbuf = lds_p[1];
#pragma unroll
    for (int ks = 0; ks < 2; ++ks) {
      f16x8 pf[4];
#pragma unroll
      for (int qt = 0; qt < 4; ++qt) pf[qt] = ldsFrag(pbuf, qt * 16 + l15, ks * 4 + l4);
#pragma unroll
      for (int qt = 0; qt < 4; ++qt)
#pragma unroll
        for (int ct = 0; ct < 4; ++ct)
          oacc[qt][ct] = MFMA16F(pf[qt], hbv[ks][ct], oacc[qt][ct]);
    }
  }

  // ---- row-sum reduction across l4-groups and waves ----
#pragma unroll
  for (int qt = 0; qt < 4; ++qt) {
    lrun[qt] += __shfl_xor(lrun[qt], 16);
    lrun[qt] += __shfl_xor(lrun[qt], 32);
  }
  if (l4 == 0) {
#pragma unroll
    for (int qt = 0; qt < 4; ++qt) lds_red[w * 64 + qt * 16 + l15] = lrun[qt];
  }
  __syncthreads();
  if (t < 64) {
    float s = (lds_red[t] + lds_red[64 + t]) + (lds_red[128 + t] + lds_red[192 + t]);
    lds_linv[t] = gamma / s;                   // fold gamma into 1/l
  }
  __syncthreads();

  // ---- epilogue: out = x + O * (gamma/l) ----
#pragma unroll
  for (int qt = 0; qt < 4; ++qt) {
    f32x4 linv = *(const f32x4*)&lds_linv[qt * 16 + (l4 << 2)];
#pragma unroll
    for (int ct = 0; ct < 4; ++ct) {
      int c = vc0 + w * 64 + ct * 16 + l15;
#pragma unroll
      for (int r = 0; r < 4; ++r) {
        int q = q0 + qt * 16 + (l4 << 2) + r;
        size_t idx = ((size_t)(b * 4096 + q) << 9) + c;
        out[idx] = x[idx] + oacc[qt][ct][r] * linv[r];
      }
    }
  }
}

extern "C" void kernel_launch(void* const* d_in, const int* in_sizes, int n_in,
                              void* d_out, int out_size, void* d_ws, size_t ws_size,
                              hipStream_t stream) {
  const float* x   = (const float*)d_in[0];
  const float* Wf  = (const float*)d_in[1];
  const float* bfv = (const float*)d_in[2];
  const float* Wg  = (const float*)d_in[3];
  const float* bgv = (const float*)d_in[4];
  const float* Wh  = (const float*)d_in[5];
  const float* bhv = (const float*)d_in[6];
  const float* gam = (const float*)d_in[7];
  float* out = (float*)d_out;

  char* ws = (char*)d_ws;                  // total scratch: ~21.6 MB
  u16*   Wt    = (u16*)(ws);               // 640*512*2   = 655360
  float* biasc = (float*)(ws + 655360);    // 640*4       = 2560
  u16*   fo    = (u16*)(ws + 657920);      // 16384*64*2  = 2097152
  u16*   go    = (u16*)(ws + 2755072);     // 2097152
  u16*   ht    = (u16*)(ws + 4852224);     // 4*512*4096*2 = 16777216

  pack_weights2<<<80, 256, 0, stream>>>(Wf, Wg, Wh, bfv, bgv, bhv, Wt, biasc);
  proj_gemm3<<<dim3(128, 5), 256, 0, stream>>>(x, Wt, biasc, fo, go, ht);
  attn6<<<512, 256, 0, stream>>>((const f16*)fo, (const f16*)go, (const f16*)ht, x, gam, out);
}